// Round 8
// baseline (1848.780 us; speedup 1.0000x reference)
//
#include <hip/hip_runtime.h>

#define H    51
#define G    153
#define BB   2048
#define TSEQ 1024
#define NB   8
#define NT   512        // 8 waves, 2/SIMD -> 256 VGPR cap
#define KP   72         // bf16 h-row stride (144B, 16B-aligned)

typedef __attribute__((ext_vector_type(8))) short short8;
typedef __attribute__((ext_vector_type(4))) float f32x4;

__device__ __forceinline__ float sigm(float x) { return 1.0f / (1.0f + __expf(-x)); }
__device__ __forceinline__ float tanh_(float x) { return 1.0f - 2.0f / (__expf(2.0f * x) + 1.0f); }
__device__ __forceinline__ unsigned short f2bf(float f) {
    unsigned u = __float_as_uint(f);
    return (unsigned short)((u + 0x7fffu + ((u >> 16) & 1u)) >> 16);   // RNE
}
__device__ __forceinline__ float bf2f(unsigned short s) { return __uint_as_float(((unsigned)s) << 16); }

#define MFMA(a, b, c) __builtin_amdgcn_mfma_f32_16x16x32_bf16((a), (b), (c), 0, 0, 0)

struct SM {
    alignas(16) short h1[2][16][KP];    // parity-buffered h1 (bf16), [n][k]
    alignas(16) short h2[2][16][KP];    // parity-buffered h2
    alignas(16) float part[2][4][8];    // out partials [parity][L2-wave][batch]
    alignas(16) float xstep[2][8][4];   // parity-buffered 4-step x chunks
    float olds[8];
};

// A-frags (hi/lo split) for tile T of gate-stacked [3H][H] matrix, 4-padded rows:
// padded row 16T+n -> element j=4T+(n>>2), gate c=n&3 (c==3 or j>=H: zero row)
__device__ __forceinline__ void loadA(const float* __restrict__ src, int T, int n, int q,
                                      short8* ah, short8* al) {
    const int jt = 4 * T + (n >> 2);
    const int c  = n & 3;
    const bool rv = (c < 3) && (jt < H);
#pragma unroll
    for (int kb = 0; kb < 2; ++kb) {
        short8 hi, lo;
#pragma unroll
        for (int jj = 0; jj < 8; ++jj) {
            const int k = kb * 32 + q * 8 + jj;
            const float v = (rv && k < H) ? src[(c * H + jt) * H + k] : 0.f;
            const unsigned short hb = f2bf(v);
            hi[jj] = (short)hb;
            lo[jj] = (short)f2bf(v - bf2f(hb));
        }
        ah[kb] = hi; al[kb] = lo;
    }
}

__device__ __forceinline__ f32x4 dotAB(const short8* ah, const short8* al, short8 b0, short8 b1) {
    f32x4 acc = {0.f, 0.f, 0.f, 0.f};
    acc = MFMA(al[0], b0, acc);
    acc = MFMA(al[1], b1, acc);
    acc = MFMA(ah[0], b0, acc);
    acc = MFMA(ah[1], b1, acc);
    return acc;
}

__global__ __launch_bounds__(NT, 2) void gru_persist(
    const float* __restrict__ inp, const int* __restrict__ fut,
    const float* __restrict__ wih1, const float* __restrict__ whh1,
    const float* __restrict__ bih1, const float* __restrict__ bhh1,
    const float* __restrict__ wih2, const float* __restrict__ whh2,
    const float* __restrict__ bih2, const float* __restrict__ bhh2,
    const float* __restrict__ wlin, const float* __restrict__ blin,
    float* __restrict__ out)
{
    __shared__ SM sm;
    const int t = threadIdx.x, bg = blockIdx.x;
    const int w = t >> 6, lane = t & 63;
    const int n = lane & 15, q = lane >> 4;
    const bool isL2 = (w >= 4);
    const int  u = isL2 ? (w - 4) : w;

    int  Tj[4]; bool tv[4]; int jj[4]; bool jv[4];
#pragma unroll
    for (int c = 0; c < 4; ++c) {
        Tj[c] = u + 4 * c;
        tv[c] = (Tj[c] < 13);
        jj[c] = 4 * Tj[c] + q;
        jv[c] = tv[c] && (jj[c] < H) && (n < NB);
    }

    // ---- A-fragments: setA = whh1 (L1) / whh2 (L2); setB = wih2 (L2 only) ----
    short8 aAh[4][2], aAl[4][2], aBh[4][2], aBl[4][2];
#pragma unroll
    for (int c = 0; c < 4; ++c) {
        loadA(isL2 ? whh2 : whh1, Tj[c], n, q, aAh[c], aAl[c]);
        loadA(wih2, Tj[c], n, q, aBh[c], aBl[c]);
    }

    // ---- per-slot constants ----
    float sb_r[4], sb_z[4], sb_n[4], sc_r[4], sc_z[4], sc_n[4], sw_r[4], sw_z[4], sw_n[4], swl[4];
#pragma unroll
    for (int c = 0; c < 4; ++c) {
        const int jcl = (tv[c] && jj[c] < H) ? jj[c] : 0;
        if (!isL2) {
            sb_r[c] = bhh1[jcl]; sb_z[c] = bhh1[H + jcl]; sb_n[c] = bhh1[2 * H + jcl];
            sw_r[c] = wih1[jcl]; sw_z[c] = wih1[H + jcl]; sw_n[c] = wih1[2 * H + jcl];
            sc_r[c] = bih1[jcl]; sc_z[c] = bih1[H + jcl]; sc_n[c] = bih1[2 * H + jcl];
            swl[c] = 0.f;
        } else {
            sb_r[c] = bhh2[jcl]; sb_z[c] = bhh2[H + jcl]; sb_n[c] = bhh2[2 * H + jcl];
            sc_r[c] = bih2[jcl]; sc_z[c] = bih2[H + jcl]; sc_n[c] = bih2[2 * H + jcl];
            sw_r[c] = 0.f; sw_z[c] = 0.f; sw_n[c] = 0.f;
            swl[c] = wlin[jcl];
        }
    }
    const float blin_r = blin[0];

    // ---- LDS init ----
    for (int i = t; i < 2 * 16 * KP; i += NT) { ((short*)sm.h1)[i] = 0; ((short*)sm.h2)[i] = 0; }
    if (t < 64) ((float*)sm.part)[t] = 0.f;
    if (t < 8) sm.olds[t] = 0.f;

    // ---- x staging: wave 2, lanes q==3 && n>=8 ----
    const bool doX = (w == 2) && (q == 3) && (n >= 8);
    const int  bs  = n - 8;
    const float* xrow = inp + (size_t)(bg * NB + (doX ? bs : 0)) * TSEQ;
    float4 xnxt = make_float4(0.f, 0.f, 0.f, 0.f);
    if (doX) {
        *(float4*)&sm.xstep[0][bs][0] = *(const float4*)xrow;   // steps 0..3
        xnxt = *(const float4*)(xrow + 4);
    }

    float h_old[4] = {0.f, 0.f, 0.f, 0.f};   // L1: h1_old per slot; L2: h2_old per slot
    float* outp = out + (size_t)(bg * NB) * ((size_t)TSEQ + (size_t)fut[0]);
    const int TT = TSEQ + fut[0];
    __syncthreads();

    // ================= MAIN LOOP: 1 barrier/step, L2 lagged by 1 =================
    for (int i = 0; i < TSEQ; ++i) {
        const int par = i & 1;

        // pipelined output flush: o(i-2)
        if (w == 1 && i >= 2) {
            const int li = lane & 31;
            float v = ((const float*)sm.part)[((par ^ 1) << 5) + li];
            v += __shfl_xor(v, 8);
            v += __shfl_xor(v, 16);
            if (lane < 8) outp[(size_t)lane * TT + (i - 2)] = v + blin_r;
        }
        if (doX && (i & 3) == 3 && i + 1 < TSEQ) {
            *(float4*)&sm.xstep[((i + 1) >> 2) & 1][bs][0] = xnxt;
            if (i + 8 < TSEQ) xnxt = *(const float4*)(xrow + i + 5);
        }

        if (!isL2) {
            // ---- L1: h1(i) = GRU1(x(i), h1(i-1)) ----
            const short8 b0 = *(const short8*)&sm.h1[par][n][q * 8];
            const short8 b1 = *(const short8*)&sm.h1[par][n][32 + q * 8];
            const float xv = sm.xstep[(i >> 2) & 1][n & 7][i & 3];
#pragma unroll
            for (int c = 0; c < 4; ++c) if (tv[c]) {
                const f32x4 a = dotAB(aAh[c], aAl[c], b0, b1);
                const float gr = sigm(fmaf(xv, sw_r[c], sc_r[c]) + a.x + sb_r[c]);
                const float gz = sigm(fmaf(xv, sw_z[c], sc_z[c]) + a.y + sb_z[c]);
                const float gn = tanh_(fmaf(gr, a.z + sb_n[c], fmaf(xv, sw_n[c], sc_n[c])));
                const float hn = (1.f - gz) * gn + gz * h_old[c];
                h_old[c] = hn;
                if (jv[c]) sm.h1[par ^ 1][n][jj[c]] = (short)f2bf(hn);
            }
        } else {
            // ---- L2: h2(i-1) = GRU2(h1(i-1), h2(i-2)) + out partials ----
            const short8 b20 = *(const short8*)&sm.h2[par][n][q * 8];
            const short8 b21 = *(const short8*)&sm.h2[par][n][32 + q * 8];
            const short8 b10 = *(const short8*)&sm.h1[par][n][q * 8];
            const short8 b11 = *(const short8*)&sm.h1[par][n][32 + q * 8];
            float pout = 0.f;
            if (i > 0) {
#pragma unroll
                for (int c = 0; c < 4; ++c) if (tv[c]) {
                    const f32x4 g  = dotAB(aAh[c], aAl[c], b20, b21);
                    const f32x4 gi = dotAB(aBh[c], aBl[c], b10, b11);
                    const float gr = sigm(gi.x + sc_r[c] + g.x + sb_r[c]);
                    const float gz = sigm(gi.y + sc_z[c] + g.y + sb_z[c]);
                    const float gn = tanh_(fmaf(gr, g.z + sb_n[c], gi.z + sc_n[c]));
                    const float hn = (1.f - gz) * gn + gz * h_old[c];
                    h_old[c] = hn;
                    if (jv[c]) { sm.h2[par ^ 1][n][jj[c]] = (short)f2bf(hn); pout = fmaf(swl[c], hn, pout); }
                }
            }
            pout += __shfl_xor(pout, 16);
            pout += __shfl_xor(pout, 32);
            if (q == 0 && n < NB) sm.part[par][u][n] = pout;
        }
        __syncthreads();
    }

    // ================= EPILOGUE: h2(1023) + flush o(1022), o(1023) =================
    if (w == 1) {
        const int li = lane & 31;
        float v = ((const float*)sm.part)[32 + li];        // parity 1 = i=1023's partials
        v += __shfl_xor(v, 8);
        v += __shfl_xor(v, 16);
        if (lane < 8) outp[(size_t)lane * TT + (TSEQ - 2)] = v + blin_r;
    }
    if (isL2) {
        const short8 b20 = *(const short8*)&sm.h2[0][n][q * 8];        // h2(1022)
        const short8 b21 = *(const short8*)&sm.h2[0][n][32 + q * 8];
        const short8 b10 = *(const short8*)&sm.h1[0][n][q * 8];        // h1(1023)
        const short8 b11 = *(const short8*)&sm.h1[0][n][32 + q * 8];
        float pout = 0.f;
#pragma unroll
        for (int c = 0; c < 4; ++c) if (tv[c]) {
            const f32x4 g  = dotAB(aAh[c], aAl[c], b20, b21);
            const f32x4 gi = dotAB(aBh[c], aBl[c], b10, b11);
            const float gr = sigm(gi.x + sc_r[c] + g.x + sb_r[c]);
            const float gz = sigm(gi.y + sc_z[c] + g.y + sb_z[c]);
            const float gn = tanh_(fmaf(gr, g.z + sb_n[c], gi.z + sc_n[c]));
            const float hn = (1.f - gz) * gn + gz * h_old[c];
            h_old[c] = hn;
            if (jv[c]) { sm.h2[1][n][jj[c]] = (short)f2bf(hn); pout = fmaf(swl[c], hn, pout); }
        }
        pout += __shfl_xor(pout, 16);
        pout += __shfl_xor(pout, 32);
        if (q == 0 && n < NB) sm.part[0][u][n] = pout;
    }
    __syncthreads();
    if (w == 1) {
        const int li = lane & 31;
        float v = ((const float*)sm.part)[li];             // parity 0 = h2(1023) partials
        v += __shfl_xor(v, 8);
        v += __shfl_xor(v, 16);
        if (lane < 8) {
            const float o = v + blin_r;
            sm.olds[lane] = o;
            outp[(size_t)lane * TT + (TSEQ - 1)] = o;
        }
    }
    __syncthreads();

    // ================= FUTURE LOOP: serial 2-phase + feedback =================
    int fp1 = 0, fh2 = 1;    // h1(1023) in h1[0], h2(1023) in h2[1]
    for (int ts = TSEQ; ts < TT; ++ts) {
        float g2r[4], g2z[4], g2n[4];
        // ---- phase A: gh1+GRU1 (L1) ; gh2 held in regs (L2) ----
        if (!isL2) {
            const float xv = sm.olds[n & 7];
            const short8 b0 = *(const short8*)&sm.h1[fp1][n][q * 8];
            const short8 b1 = *(const short8*)&sm.h1[fp1][n][32 + q * 8];
#pragma unroll
            for (int c = 0; c < 4; ++c) if (tv[c]) {
                const f32x4 a = dotAB(aAh[c], aAl[c], b0, b1);
                const float gr = sigm(fmaf(xv, sw_r[c], sc_r[c]) + a.x + sb_r[c]);
                const float gz = sigm(fmaf(xv, sw_z[c], sc_z[c]) + a.y + sb_z[c]);
                const float gn = tanh_(fmaf(gr, a.z + sb_n[c], fmaf(xv, sw_n[c], sc_n[c])));
                const float hn = (1.f - gz) * gn + gz * h_old[c];
                h_old[c] = hn;
                if (jv[c]) sm.h1[fp1 ^ 1][n][jj[c]] = (short)f2bf(hn);
            }
        } else {
            const short8 b20 = *(const short8*)&sm.h2[fh2][n][q * 8];
            const short8 b21 = *(const short8*)&sm.h2[fh2][n][32 + q * 8];
#pragma unroll
            for (int c = 0; c < 4; ++c) if (tv[c]) {
                const f32x4 g = dotAB(aAh[c], aAl[c], b20, b21);
                g2r[c] = g.x + sb_r[c]; g2z[c] = g.y + sb_z[c]; g2n[c] = g.z + sb_n[c];
            }
        }
        __syncthreads();
        // ---- phase B: gi2+GRU2+partials (L2) ----
        if (isL2) {
            const short8 b10 = *(const short8*)&sm.h1[fp1 ^ 1][n][q * 8];
            const short8 b11 = *(const short8*)&sm.h1[fp1 ^ 1][n][32 + q * 8];
            float pout = 0.f;
#pragma unroll
            for (int c = 0; c < 4; ++c) if (tv[c]) {
                const f32x4 gi = dotAB(aBh[c], aBl[c], b10, b11);
                const float gr = sigm(gi.x + sc_r[c] + g2r[c]);
                const float gz = sigm(gi.y + sc_z[c] + g2z[c]);
                const float gn = tanh_(fmaf(gr, g2n[c], gi.z + sc_n[c]));
                const float hn = (1.f - gz) * gn + gz * h_old[c];
                h_old[c] = hn;
                if (jv[c]) { sm.h2[fh2 ^ 1][n][jj[c]] = (short)f2bf(hn); pout = fmaf(swl[c], hn, pout); }
            }
            pout += __shfl_xor(pout, 16);
            pout += __shfl_xor(pout, 32);
            if (q == 0 && n < NB) sm.part[0][u][n] = pout;
        }
        __syncthreads();
        // ---- phase C: reduce + feedback ----
        if (w == 1) {
            const int li = lane & 31;
            float v = ((const float*)sm.part)[li];
            v += __shfl_xor(v, 8);
            v += __shfl_xor(v, 16);
            if (lane < 8) {
                const float o = v + blin_r;
                sm.olds[lane] = o;
                outp[(size_t)lane * TT + ts] = o;
            }
        }
        __syncthreads();
        fp1 ^= 1; fh2 ^= 1;
    }
}

extern "C" void kernel_launch(void* const* d_in, const int* in_sizes, int n_in,
                              void* d_out, int out_size, void* d_ws, size_t ws_size,
                              hipStream_t stream) {
    (void)in_sizes; (void)n_in; (void)d_ws; (void)ws_size; (void)out_size;
    gru_persist<<<BB / NB, NT, 0, stream>>>(
        (const float*)d_in[0], (const int*)d_in[1],
        (const float*)d_in[2], (const float*)d_in[3], (const float*)d_in[4], (const float*)d_in[5],
        (const float*)d_in[6], (const float*)d_in[7], (const float*)d_in[8], (const float*)d_in[9],
        (const float*)d_in[10], (const float*)d_in[11],
        (float*)d_out);
}

// Round 9
// 1830.860 us; speedup vs baseline: 1.0098x; 1.0098x over previous
//
#include <hip/hip_runtime.h>

#define H    51
#define G    153
#define BB   2048
#define TSEQ 1024
#define NB   8
#define NT   1024       // 16 waves, 4/SIMD
#define KP   72         // bf16 h-row stride (144B, 16B-aligned)

typedef __attribute__((ext_vector_type(8))) short short8;
typedef __attribute__((ext_vector_type(4))) float f32x4;

__device__ __forceinline__ float sigm(float x) { return 1.0f / (1.0f + __expf(-x)); }
__device__ __forceinline__ float tanh_(float x) { return 1.0f - 2.0f / (__expf(2.0f * x) + 1.0f); }
__device__ __forceinline__ unsigned short f2bf(float f) {
    unsigned u = __float_as_uint(f);
    return (unsigned short)((u + 0x7fffu + ((u >> 16) & 1u)) >> 16);   // RNE
}
__device__ __forceinline__ float bf2f(unsigned short s) { return __uint_as_float(((unsigned)s) << 16); }

#define MFMA(a, b, c) __builtin_amdgcn_mfma_f32_16x16x32_bf16((a), (b), (c), 0, 0, 0)

struct SM {
    alignas(16) short h1[2][16][KP];    // parity-buffered h1 (bf16), [n][k]
    alignas(16) short h2[2][16][KP];    // parity-buffered h2
    alignas(16) float part[2][16][8];   // out partials [parity][tile][batch]
    alignas(16) float xstep[2][8][4];   // parity-buffered 4-step x chunks
    float olds[8];
};

// A-frags (hi/lo split) for tile T of gate-stacked [3H][H] matrix, 4-padded rows:
// padded row 16T+n -> element j=4T+(n>>2), gate c=n&3 (c==3 or j>=H: zero row)
__device__ __forceinline__ void loadA(const float* __restrict__ src, int T, int n, int q,
                                      short8* ah, short8* al) {
    const int jt = 4 * T + (n >> 2);
    const int c  = n & 3;
    const bool rv = (c < 3) && (jt < H);
#pragma unroll
    for (int kb = 0; kb < 2; ++kb) {
        short8 hi, lo;
#pragma unroll
        for (int jj = 0; jj < 8; ++jj) {
            const int k = kb * 32 + q * 8 + jj;
            const float v = (rv && k < H) ? src[(c * H + jt) * H + k] : 0.f;
            const unsigned short hb = f2bf(v);
            hi[jj] = (short)hb;
            lo[jj] = (short)f2bf(v - bf2f(hb));
        }
        ah[kb] = hi; al[kb] = lo;
    }
}

// 2-term split matvec; dual accumulators -> dependent chain of 2 MFMAs
__device__ __forceinline__ f32x4 dot2(const short8* ah, const short8* al, short8 b0, short8 b1) {
    f32x4 x = {0.f, 0.f, 0.f, 0.f}, y = {0.f, 0.f, 0.f, 0.f};
    x = MFMA(al[0], b0, x);
    x = MFMA(al[1], b1, x);
    y = MFMA(ah[0], b0, y);
    y = MFMA(ah[1], b1, y);
    return x + y;
}

__global__ __launch_bounds__(NT, 1) void gru_persist(
    const float* __restrict__ inp, const int* __restrict__ fut,
    const float* __restrict__ wih1, const float* __restrict__ whh1,
    const float* __restrict__ bih1, const float* __restrict__ bhh1,
    const float* __restrict__ wih2, const float* __restrict__ whh2,
    const float* __restrict__ bih2, const float* __restrict__ bhh2,
    const float* __restrict__ wlin, const float* __restrict__ blin,
    float* __restrict__ out)
{
    __shared__ SM sm;
    const int t = threadIdx.x, bg = blockIdx.x;
    const int w = t >> 6, lane = t & 63;
    const int n = lane & 15, q = lane >> 4;
    const bool doM = (w < 13);                 // matvec waves: one tile triple each
    const int  T   = doM ? w : 0;
    const int  j   = 4 * T + q;
    const bool jv  = doM && (j < H) && (n < NB);
    const int  jcl = (j < H) ? j : 0;

    // ---- A-fragments: 12 short8 = 48 VGPRs ----
    short8 a1h[2], a1l[2], a2h[2], a2l[2], a3h[2], a3l[2];
    loadA(whh1, T, n, q, a1h, a1l);
    loadA(whh2, T, n, q, a2h, a2l);
    loadA(wih2, T, n, q, a3h, a3l);

    // ---- per-lane scalar constants ----
    const float b1r = bhh1[jcl], b1z = bhh1[H + jcl], b1n = bhh1[2 * H + jcl];
    const float w1r = wih1[jcl], w1z = wih1[H + jcl], w1n = wih1[2 * H + jcl];
    const float c1r = bih1[jcl], c1z = bih1[H + jcl], c1n = bih1[2 * H + jcl];
    const float b2r = bhh2[jcl], b2z = bhh2[H + jcl], b2n = bhh2[2 * H + jcl];
    const float c2r = bih2[jcl], c2z = bih2[H + jcl], c2n = bih2[2 * H + jcl];
    const float wl  = wlin[jcl];
    const float blin_r = blin[0];

    // ---- LDS init ----
    for (int i = t; i < 2 * 16 * KP; i += NT) { ((short*)sm.h1)[i] = 0; ((short*)sm.h2)[i] = 0; }
    if (t < 256) ((float*)sm.part)[t] = 0.f;
    if (t < 8) sm.olds[t] = 0.f;

    // ---- x staging: wave 13, lanes 0..7 ----
    const bool doX = (w == 13) && (lane < 8);
    const int  bs  = lane;
    const float* xrow = inp + (size_t)(bg * NB + (doX ? bs : 0)) * TSEQ;
    float4 xnxt = make_float4(0.f, 0.f, 0.f, 0.f);
    if (doX) {
        *(float4*)&sm.xstep[0][bs][0] = *(const float4*)xrow;   // steps 0..3
        xnxt = *(const float4*)(xrow + 4);                      // steps 4..7
    }

    float h1o = 0.f, h2o = 0.f;     // per-lane f32 hidden (element j, batch n)
    const int TT = TSEQ + fut[0];
    float* outp = out + (size_t)(bg * NB) * (size_t)TT;
    __syncthreads();

    // ================= MAIN LOOP: both layers advance per step, 2 barriers =================
    for (int i = 0; i < TSEQ; ++i) {
        const int par = i & 1;
        float g2r, g2z, g2n;

        if (doM) {
            // ---- phase A: gh2 (hold) + gh1+GRU1 ----
            const short8 b10 = *(const short8*)&sm.h1[par][n][q * 8];
            const short8 b11 = *(const short8*)&sm.h1[par][n][32 + q * 8];
            const short8 b20 = *(const short8*)&sm.h2[par][n][q * 8];
            const short8 b21 = *(const short8*)&sm.h2[par][n][32 + q * 8];
            const float  xv  = sm.xstep[(i >> 2) & 1][n & 7][i & 3];
            {
                const f32x4 g = dot2(a2h, a2l, b20, b21);
                g2r = g.x + b2r; g2z = g.y + b2z; g2n = g.z + b2n;
            }
            {
                const f32x4 a = dot2(a1h, a1l, b10, b11);
                const float gr = sigm(fmaf(xv, w1r, c1r) + a.x + b1r);
                const float gz = sigm(fmaf(xv, w1z, c1z) + a.y + b1z);
                const float gn = tanh_(fmaf(gr, a.z + b1n, fmaf(xv, w1n, c1n)));
                const float hn = (1.f - gz) * gn + gz * h1o;
                h1o = hn;
                if (jv) sm.h1[par ^ 1][n][j] = (short)f2bf(hn);
            }
        } else if (w == 14 && i > 0) {
            // ---- pipelined output reduction: o(i-1) ----
            const float* pb = &sm.part[par ^ 1][0][0];
            float v = pb[lane] + pb[64 + lane];
            v += __shfl_xor(v, 8);
            v += __shfl_xor(v, 16);
            v += __shfl_xor(v, 32);
            if (lane < 8) outp[(size_t)lane * TT + (i - 1)] = v + blin_r;
        } else if (doX && (i & 3) == 3 && i + 1 < TSEQ) {
            *(float4*)&sm.xstep[((i + 1) >> 2) & 1][bs][0] = xnxt;
            if (i + 8 < TSEQ) xnxt = *(const float4*)(xrow + i + 5);
        }
        __syncthreads();

        if (doM) {
            // ---- phase B: gi2 + GRU2 + out partial ----
            const short8 c0 = *(const short8*)&sm.h1[par ^ 1][n][q * 8];
            const short8 c1 = *(const short8*)&sm.h1[par ^ 1][n][32 + q * 8];
            const f32x4 gi = dot2(a3h, a3l, c0, c1);
            const float gr = sigm(gi.x + c2r + g2r);
            const float gz = sigm(gi.y + c2z + g2z);
            const float gn = tanh_(fmaf(gr, g2n, gi.z + c2n));
            const float hn = (1.f - gz) * gn + gz * h2o;
            h2o = hn;
            float pout = 0.f;
            if (jv) { sm.h2[par ^ 1][n][j] = (short)f2bf(hn); pout = wl * hn; }
            pout += __shfl_xor(pout, 16);
            pout += __shfl_xor(pout, 32);
            if (q == 0 && n < NB) sm.part[par][T][n] = pout;
        }
        __syncthreads();
    }

    // ---- flush o(TSEQ-1), seed olds ----
    if (w == 14) {
        const float* pb = &sm.part[(TSEQ - 1) & 1][0][0];
        float v = pb[lane] + pb[64 + lane];
        v += __shfl_xor(v, 8);
        v += __shfl_xor(v, 16);
        v += __shfl_xor(v, 32);
        if (lane < 8) {
            const float o = v + blin_r;
            sm.olds[lane] = o;
            outp[(size_t)lane * TT + (TSEQ - 1)] = o;
        }
    }
    __syncthreads();

    // ================= FUTURE LOOP: serial, 3 barriers/step =================
    int fp = 0;    // current state lives in buffer 0 (written at i=1023, par=1)
    for (int ts = TSEQ; ts < TT; ++ts) {
        float g2r, g2z, g2n;
        if (doM) {
            const short8 b10 = *(const short8*)&sm.h1[fp][n][q * 8];
            const short8 b11 = *(const short8*)&sm.h1[fp][n][32 + q * 8];
            const short8 b20 = *(const short8*)&sm.h2[fp][n][q * 8];
            const short8 b21 = *(const short8*)&sm.h2[fp][n][32 + q * 8];
            const float  xv  = sm.olds[n & 7];
            {
                const f32x4 g = dot2(a2h, a2l, b20, b21);
                g2r = g.x + b2r; g2z = g.y + b2z; g2n = g.z + b2n;
            }
            {
                const f32x4 a = dot2(a1h, a1l, b10, b11);
                const float gr = sigm(fmaf(xv, w1r, c1r) + a.x + b1r);
                const float gz = sigm(fmaf(xv, w1z, c1z) + a.y + b1z);
                const float gn = tanh_(fmaf(gr, a.z + b1n, fmaf(xv, w1n, c1n)));
                const float hn = (1.f - gz) * gn + gz * h1o;
                h1o = hn;
                if (jv) sm.h1[fp ^ 1][n][j] = (short)f2bf(hn);
            }
        }
        __syncthreads();
        if (doM) {
            const short8 c0 = *(const short8*)&sm.h1[fp ^ 1][n][q * 8];
            const short8 c1 = *(const short8*)&sm.h1[fp ^ 1][n][32 + q * 8];
            const f32x4 gi = dot2(a3h, a3l, c0, c1);
            const float gr = sigm(gi.x + c2r + g2r);
            const float gz = sigm(gi.y + c2z + g2z);
            const float gn = tanh_(fmaf(gr, g2n, gi.z + c2n));
            const float hn = (1.f - gz) * gn + gz * h2o;
            h2o = hn;
            float pout = 0.f;
            if (jv) { sm.h2[fp ^ 1][n][j] = (short)f2bf(hn); pout = wl * hn; }
            pout += __shfl_xor(pout, 16);
            pout += __shfl_xor(pout, 32);
            if (q == 0 && n < NB) sm.part[0][T][n] = pout;
        }
        __syncthreads();
        if (w == 14) {
            const float* pb = &sm.part[0][0][0];
            float v = pb[lane] + pb[64 + lane];
            v += __shfl_xor(v, 8);
            v += __shfl_xor(v, 16);
            v += __shfl_xor(v, 32);
            if (lane < 8) {
                const float o = v + blin_r;
                sm.olds[lane] = o;
                outp[(size_t)lane * TT + ts] = o;
            }
        }
        __syncthreads();
        fp ^= 1;
    }
}

extern "C" void kernel_launch(void* const* d_in, const int* in_sizes, int n_in,
                              void* d_out, int out_size, void* d_ws, size_t ws_size,
                              hipStream_t stream) {
    (void)in_sizes; (void)n_in; (void)d_ws; (void)ws_size; (void)out_size;
    gru_persist<<<BB / NB, NT, 0, stream>>>(
        (const float*)d_in[0], (const int*)d_in[1],
        (const float*)d_in[2], (const float*)d_in[3], (const float*)d_in[4], (const float*)d_in[5],
        (const float*)d_in[6], (const float*)d_in[7], (const float*)d_in[8], (const float*)d_in[9],
        (const float*)d_in[10], (const float*)d_in[11],
        (float*)d_out);
}

// Round 10
// 1522.137 us; speedup vs baseline: 1.2146x; 1.2028x over previous
//
#include <hip/hip_runtime.h>

#define H    51
#define G    153
#define BB   2048
#define TSEQ 1024
#define NB   8
#define NT   1024       // 16 waves, 4/SIMD
#define KP   72         // bf16 h-row stride (144B, 16B-aligned)

typedef __attribute__((ext_vector_type(8))) short short8;
typedef __attribute__((ext_vector_type(4))) float f32x4;

__device__ __forceinline__ float sigm(float x) { return 1.0f / (1.0f + __expf(-x)); }
__device__ __forceinline__ float tanh_(float x) { return 1.0f - 2.0f / (__expf(2.0f * x) + 1.0f); }
__device__ __forceinline__ unsigned short f2bf(float f) {
    unsigned u = __float_as_uint(f);
    return (unsigned short)((u + 0x7fffu + ((u >> 16) & 1u)) >> 16);   // RNE
}
__device__ __forceinline__ float bf2f(unsigned short s) { return __uint_as_float(((unsigned)s) << 16); }

#define MFMA(a, b, c) __builtin_amdgcn_mfma_f32_16x16x32_bf16((a), (b), (c), 0, 0, 0)

struct SM {
    alignas(16) short h1[2][16][KP];    // parity-buffered h1 (bf16), [n][k]
    alignas(16) short h2[2][16][KP];    // parity-buffered h2
    alignas(16) float part[2][16][8];   // out partials [parity][tile][batch]
    alignas(16) float xstep[2][8][4];   // parity-buffered 4-step x chunks
    float olds[8];
};

// A-frags (hi/lo split) for tile T of gate-stacked [3H][H] matrix, 4-padded rows:
// padded row 16T+n -> element j=4T+(n>>2), gate c=n&3 (c==3 or j>=H: zero row)
__device__ __forceinline__ void loadA(const float* __restrict__ src, int T, int n, int q,
                                      short8* ah, short8* al) {
    const int jt = 4 * T + (n >> 2);
    const int c  = n & 3;
    const bool rv = (c < 3) && (jt < H);
#pragma unroll
    for (int kb = 0; kb < 2; ++kb) {
        short8 hi, lo;
#pragma unroll
        for (int jj = 0; jj < 8; ++jj) {
            const int k = kb * 32 + q * 8 + jj;
            const float v = (rv && k < H) ? src[(c * H + jt) * H + k] : 0.f;
            const unsigned short hb = f2bf(v);
            hi[jj] = (short)hb;
            lo[jj] = (short)f2bf(v - bf2f(hb));
        }
        ah[kb] = hi; al[kb] = lo;
    }
}

// 2-term split matvec with bias folded into accumulator init
__device__ __forceinline__ f32x4 dot2i(const short8* ah, const short8* al,
                                       short8 b0, short8 b1, f32x4 init) {
    f32x4 x = init, y = {0.f, 0.f, 0.f, 0.f};
    x = MFMA(al[0], b0, x);
    x = MFMA(al[1], b1, x);
    y = MFMA(ah[0], b0, y);
    y = MFMA(ah[1], b1, y);
    return x + y;
}

__global__ __launch_bounds__(NT, 1) void gru_persist(
    const float* __restrict__ inp, const int* __restrict__ fut,
    const float* __restrict__ wih1, const float* __restrict__ whh1,
    const float* __restrict__ bih1, const float* __restrict__ bhh1,
    const float* __restrict__ wih2, const float* __restrict__ whh2,
    const float* __restrict__ bih2, const float* __restrict__ bhh2,
    const float* __restrict__ wlin, const float* __restrict__ blin,
    float* __restrict__ out)
{
    __shared__ SM sm;
    const int t = threadIdx.x, bg = blockIdx.x;
    const int w = t >> 6, lane = t & 63;
    const int n = lane & 15, q = lane >> 4;
    const bool doM = (w < 13);                 // matvec waves: one tile triple each
    const int  T   = doM ? w : 0;
    const int  j   = 4 * T + q;
    const bool jv  = doM && (j < H) && (n < NB);
    const int  jcl = (j < H) ? j : 0;

    // ---- A-fragments: 12 short8 = 48 VGPRs ----
    short8 a1h[2], a1l[2], a2h[2], a2l[2], a3h[2], a3l[2];
    loadA(whh1, T, n, q, a1h, a1l);
    loadA(whh2, T, n, q, a2h, a2l);
    loadA(wih2, T, n, q, a3h, a3l);

    // ---- per-lane constants; biases as f32x4 accumulator inits ----
    const f32x4 b1v = {bhh1[jcl], bhh1[H + jcl], bhh1[2 * H + jcl], 0.f};
    const f32x4 b2v = {bhh2[jcl], bhh2[H + jcl], bhh2[2 * H + jcl], 0.f};
    const f32x4 c2v = {bih2[jcl], bih2[H + jcl], bih2[2 * H + jcl], 0.f};
    const float w1r = wih1[jcl], w1z = wih1[H + jcl], w1n = wih1[2 * H + jcl];
    const float c1r = bih1[jcl], c1z = bih1[H + jcl], c1n = bih1[2 * H + jcl];
    const float wl  = wlin[jcl];
    const float blin_r = blin[0];

    // ---- LDS init ----
    for (int i = t; i < 2 * 16 * KP; i += NT) { ((short*)sm.h1)[i] = 0; ((short*)sm.h2)[i] = 0; }
    if (t < 256) ((float*)sm.part)[t] = 0.f;
    if (t < 8) sm.olds[t] = 0.f;

    // ---- x staging: wave 13, lanes 0..7 ----
    const bool doX = (w == 13) && (lane < 8);
    const int  bs  = lane;
    const float* xrow = inp + (size_t)(bg * NB + (doX ? bs : 0)) * TSEQ;
    float4 xnxt = make_float4(0.f, 0.f, 0.f, 0.f);
    if (doX) {
        *(float4*)&sm.xstep[0][bs][0] = *(const float4*)xrow;   // steps 0..3
        xnxt = *(const float4*)(xrow + 4);                      // steps 4..7
    }

    float h1o = 0.f, h2o = 0.f;     // per-lane f32 hidden (element j, batch n)
    const int TT = TSEQ + fut[0];
    float* outp = out + (size_t)(bg * NB) * (size_t)TT;
    __syncthreads();

    // ========== MAIN LOOP: L2 lagged 1 step -> ONE phase, ONE barrier ==========
    for (int i = 0; i < TSEQ; ++i) {
        const int par = i & 1;
        if (doM) {
            const short8 b10 = *(const short8*)&sm.h1[par][n][q * 8];       // h1(i-1)
            const short8 b11 = *(const short8*)&sm.h1[par][n][32 + q * 8];
            const short8 b20 = *(const short8*)&sm.h2[par][n][q * 8];       // h2(i-2)
            const short8 b21 = *(const short8*)&sm.h2[par][n][32 + q * 8];
            const float  xv  = sm.xstep[(i >> 2) & 1][n & 7][i & 3];
            if (i > 0) {
                // ---- L2: h2(i-1) = GRU2(h1(i-1), h2(i-2)) ----
                const f32x4 g  = dot2i(a2h, a2l, b20, b21, b2v);
                const f32x4 gi = dot2i(a3h, a3l, b10, b11, c2v);
                const float gr = sigm(gi.x + g.x);
                const float gz = sigm(gi.y + g.y);
                const float gn = tanh_(fmaf(gr, g.z, gi.z));
                const float hn = (1.f - gz) * gn + gz * h2o;
                h2o = hn;
                float pout = 0.f;
                if (jv) { sm.h2[par ^ 1][n][j] = (short)f2bf(hn); pout = wl * hn; }
                pout += __shfl_xor(pout, 16);
                pout += __shfl_xor(pout, 32);
                if (q == 0 && n < NB) sm.part[par][T][n] = pout;    // o(i-1) partials
            }
            {
                // ---- L1: h1(i) = GRU1(x(i), h1(i-1)) ----
                const f32x4 a = dot2i(a1h, a1l, b10, b11, b1v);
                const float gr = sigm(fmaf(xv, w1r, c1r) + a.x);
                const float gz = sigm(fmaf(xv, w1z, c1z) + a.y);
                const float gn = tanh_(fmaf(gr, a.z, fmaf(xv, w1n, c1n)));
                const float hn = (1.f - gz) * gn + gz * h1o;
                h1o = hn;
                if (jv) sm.h1[par ^ 1][n][j] = (short)f2bf(hn);
            }
        } else if (w == 14 && i >= 2) {
            // ---- pipelined output reduction: o(i-2) ----
            const float* pb = &sm.part[par ^ 1][0][0];
            float v = pb[lane] + pb[64 + lane];
            v += __shfl_xor(v, 8);
            v += __shfl_xor(v, 16);
            v += __shfl_xor(v, 32);
            if (lane < 8) outp[(size_t)lane * TT + (i - 2)] = v + blin_r;
        } else if (doX && (i & 3) == 3 && i + 1 < TSEQ) {
            *(float4*)&sm.xstep[((i + 1) >> 2) & 1][bs][0] = xnxt;
            if (i + 8 < TSEQ) xnxt = *(const float4*)(xrow + i + 5);
        }
        __syncthreads();
    }

    // ========== EPILOGUE: h2(TSEQ-1), flush o(TSEQ-2) and o(TSEQ-1) ==========
    // state: h1(TSEQ-1) in h1[0], h2(TSEQ-2) in h2[0]; part[1] holds o(TSEQ-2) partials
    if (doM) {
        const short8 b10 = *(const short8*)&sm.h1[0][n][q * 8];
        const short8 b11 = *(const short8*)&sm.h1[0][n][32 + q * 8];
        const short8 b20 = *(const short8*)&sm.h2[0][n][q * 8];
        const short8 b21 = *(const short8*)&sm.h2[0][n][32 + q * 8];
        const f32x4 g  = dot2i(a2h, a2l, b20, b21, b2v);
        const f32x4 gi = dot2i(a3h, a3l, b10, b11, c2v);
        const float gr = sigm(gi.x + g.x);
        const float gz = sigm(gi.y + g.y);
        const float gn = tanh_(fmaf(gr, g.z, gi.z));
        const float hn = (1.f - gz) * gn + gz * h2o;
        h2o = hn;
        float pout = 0.f;
        if (jv) { sm.h2[1][n][j] = (short)f2bf(hn); pout = wl * hn; }
        pout += __shfl_xor(pout, 16);
        pout += __shfl_xor(pout, 32);
        if (q == 0 && n < NB) sm.part[0][T][n] = pout;
    } else if (w == 14) {
        const float* pb = &sm.part[1][0][0];
        float v = pb[lane] + pb[64 + lane];
        v += __shfl_xor(v, 8);
        v += __shfl_xor(v, 16);
        v += __shfl_xor(v, 32);
        if (lane < 8) outp[(size_t)lane * TT + (TSEQ - 2)] = v + blin_r;
    }
    __syncthreads();
    if (w == 14) {
        const float* pb = &sm.part[0][0][0];
        float v = pb[lane] + pb[64 + lane];
        v += __shfl_xor(v, 8);
        v += __shfl_xor(v, 16);
        v += __shfl_xor(v, 32);
        if (lane < 8) {
            const float o = v + blin_r;
            sm.olds[lane] = o;
            outp[(size_t)lane * TT + (TSEQ - 1)] = o;
        }
    }
    __syncthreads();

    // ========== FUTURE LOOP: serial feedback, 3 barriers/step ==========
    int fp1 = 0, fh2 = 1;    // h1(TSEQ-1) in h1[0], h2(TSEQ-1) in h2[1]
    for (int ts = TSEQ; ts < TT; ++ts) {
        float g2r, g2z, g2n;
        if (doM) {
            const short8 b10 = *(const short8*)&sm.h1[fp1][n][q * 8];
            const short8 b11 = *(const short8*)&sm.h1[fp1][n][32 + q * 8];
            const short8 b20 = *(const short8*)&sm.h2[fh2][n][q * 8];
            const short8 b21 = *(const short8*)&sm.h2[fh2][n][32 + q * 8];
            const float  xv  = sm.olds[n & 7];
            {
                const f32x4 g = dot2i(a2h, a2l, b20, b21, b2v);
                g2r = g.x; g2z = g.y; g2n = g.z;
            }
            {
                const f32x4 a = dot2i(a1h, a1l, b10, b11, b1v);
                const float gr = sigm(fmaf(xv, w1r, c1r) + a.x);
                const float gz = sigm(fmaf(xv, w1z, c1z) + a.y);
                const float gn = tanh_(fmaf(gr, a.z, fmaf(xv, w1n, c1n)));
                const float hn = (1.f - gz) * gn + gz * h1o;
                h1o = hn;
                if (jv) sm.h1[fp1 ^ 1][n][j] = (short)f2bf(hn);
            }
        }
        __syncthreads();
        if (doM) {
            const short8 c0 = *(const short8*)&sm.h1[fp1 ^ 1][n][q * 8];
            const short8 c1 = *(const short8*)&sm.h1[fp1 ^ 1][n][32 + q * 8];
            const f32x4 gi = dot2i(a3h, a3l, c0, c1, c2v);
            const float gr = sigm(gi.x + g2r);
            const float gz = sigm(gi.y + g2z);
            const float gn = tanh_(fmaf(gr, g2n, gi.z));
            const float hn = (1.f - gz) * gn + gz * h2o;
            h2o = hn;
            float pout = 0.f;
            if (jv) { sm.h2[fh2 ^ 1][n][j] = (short)f2bf(hn); pout = wl * hn; }
            pout += __shfl_xor(pout, 16);
            pout += __shfl_xor(pout, 32);
            if (q == 0 && n < NB) sm.part[0][T][n] = pout;
        }
        __syncthreads();
        if (w == 14) {
            const float* pb = &sm.part[0][0][0];
            float v = pb[lane] + pb[64 + lane];
            v += __shfl_xor(v, 8);
            v += __shfl_xor(v, 16);
            v += __shfl_xor(v, 32);
            if (lane < 8) {
                const float o = v + blin_r;
                sm.olds[lane] = o;
                outp[(size_t)lane * TT + ts] = o;
            }
        }
        __syncthreads();
        fp1 ^= 1; fh2 ^= 1;
    }
}

extern "C" void kernel_launch(void* const* d_in, const int* in_sizes, int n_in,
                              void* d_out, int out_size, void* d_ws, size_t ws_size,
                              hipStream_t stream) {
    (void)in_sizes; (void)n_in; (void)d_ws; (void)ws_size; (void)out_size;
    gru_persist<<<BB / NB, NT, 0, stream>>>(
        (const float*)d_in[0], (const int*)d_in[1],
        (const float*)d_in[2], (const float*)d_in[3], (const float*)d_in[4], (const float*)d_in[5],
        (const float*)d_in[6], (const float*)d_in[7], (const float*)d_in[8], (const float*)d_in[9],
        (const float*)d_in[10], (const float*)d_in[11],
        (float*)d_out);
}

// Round 12
// 1412.244 us; speedup vs baseline: 1.3091x; 1.0778x over previous
//
#include <hip/hip_runtime.h>

#define H    51
#define G    153
#define BB   2048
#define TSEQ 1024
#define NB   8
#define NT   1024       // 16 waves, 4/SIMD
#define KP   72         // bf16 h-row stride (144B, 16B-aligned)

typedef __attribute__((ext_vector_type(8))) short short8;
typedef __attribute__((ext_vector_type(4))) float f32x4;

__device__ __forceinline__ float sigm(float x) { return 1.0f / (1.0f + __expf(-x)); }
__device__ __forceinline__ float tanh_(float x) { return 1.0f - 2.0f / (__expf(2.0f * x) + 1.0f); }
__device__ __forceinline__ unsigned short f2bf(float f) {
    unsigned u = __float_as_uint(f);
    return (unsigned short)((u + 0x7fffu + ((u >> 16) & 1u)) >> 16);   // RNE
}
__device__ __forceinline__ float bf2f(unsigned short s) { return __uint_as_float(((unsigned)s) << 16); }

#define MFMA(a, b, c) __builtin_amdgcn_mfma_f32_16x16x32_bf16((a), (b), (c), 0, 0, 0)

struct SM {
    alignas(16) short h1[2][16][KP];    // parity-buffered h1 (bf16), [n][k]
    alignas(16) short h2[2][16][KP];    // parity-buffered h2
    alignas(16) float part[2][16][8];   // out partials [parity][tile][batch]
    alignas(16) float xstep[2][8][4];   // parity-chunked x staging [buf][batch][slot]
    float olds[8];
};

// A-frags (hi/lo split) for tile T of gate-stacked [3H][H] matrix, 4-padded rows:
// padded row 16T+n -> element j=4T+(n>>2), gate c=n&3 (c==3 or j>=H: zero row)
__device__ __forceinline__ void loadA(const float* __restrict__ src, int T, int n, int q,
                                      short8* ah, short8* al) {
    const int jt = 4 * T + (n >> 2);
    const int c  = n & 3;
    const bool rv = (c < 3) && (jt < H);
#pragma unroll
    for (int kb = 0; kb < 2; ++kb) {
        short8 hi, lo;
#pragma unroll
        for (int jj = 0; jj < 8; ++jj) {
            const int k = kb * 32 + q * 8 + jj;
            const float v = (rv && k < H) ? src[(c * H + jt) * H + k] : 0.f;
            const unsigned short hb = f2bf(v);
            hi[jj] = (short)hb;
            lo[jj] = (short)f2bf(v - bf2f(hb));
        }
        ah[kb] = hi; al[kb] = lo;
    }
}

// chained 4-MFMA 2-term split matvec, bias folded into accumulator init
__device__ __forceinline__ f32x4 dot4(const short8* ah, const short8* al,
                                      short8 b0, short8 b1, f32x4 init) {
    f32x4 acc = init;
    acc = MFMA(al[0], b0, acc);
    acc = MFMA(al[1], b1, acc);
    acc = MFMA(ah[0], b0, acc);
    acc = MFMA(ah[1], b1, acc);
    return acc;
}

__global__ __launch_bounds__(NT, 1) void gru_persist(
    const float* __restrict__ inp, const int* __restrict__ fut,
    const float* __restrict__ wih1, const float* __restrict__ whh1,
    const float* __restrict__ bih1, const float* __restrict__ bhh1,
    const float* __restrict__ wih2, const float* __restrict__ whh2,
    const float* __restrict__ bih2, const float* __restrict__ bhh2,
    const float* __restrict__ wlin, const float* __restrict__ blin,
    float* __restrict__ out)
{
    __shared__ SM sm;
    const int t = threadIdx.x, bg = blockIdx.x;
    const int w = t >> 6, lane = t & 63;
    const int n = lane & 15, q = lane >> 4;
    const bool doM = (w < 13);                 // matvec waves: one tile triple each
    const int  T   = doM ? w : 0;
    const int  j   = 4 * T + q;
    const bool jv  = doM && (j < H) && (n < NB);
    const int  jcl = (j < H) ? j : 0;

    // ---- A-fragments: 12 short8 = 48 VGPRs ----
    short8 a1h[2], a1l[2], a2h[2], a2l[2], a3h[2], a3l[2];
    loadA(whh1, T, n, q, a1h, a1l);
    loadA(whh2, T, n, q, a2h, a2l);
    loadA(wih2, T, n, q, a3h, a3l);

    // ---- per-lane constants; biases as f32x4 accumulator inits ----
    const f32x4 b1v = {bhh1[jcl], bhh1[H + jcl], bhh1[2 * H + jcl], 0.f};
    const f32x4 b2v = {bhh2[jcl], bhh2[H + jcl], bhh2[2 * H + jcl], 0.f};
    const f32x4 c2v = {bih2[jcl], bih2[H + jcl], bih2[2 * H + jcl], 0.f};
    const float w1r = wih1[jcl], w1z = wih1[H + jcl], w1n = wih1[2 * H + jcl];
    const float c1r = bih1[jcl], c1z = bih1[H + jcl], c1n = bih1[2 * H + jcl];
    const float wl  = wlin[jcl];
    const float blin_r = blin[0];

    // ---- LDS init ----
    for (int i = t; i < 2 * 16 * KP; i += NT) { ((short*)sm.h1)[i] = 0; ((short*)sm.h2)[i] = 0; }
    if (t < 256) ((float*)sm.part)[t] = 0.f;
    if (t < 8) sm.olds[t] = 0.f;

    // ---- x staging: wave 13, lanes 0..7; parity-chunked double buffer ----
    const bool doX = (w == 13) && (lane < 8);
    const int  bs  = lane;
    const float* xrow = inp + (size_t)(bg * NB + (doX ? bs : 0)) * TSEQ;
    float4 xnxt = make_float4(0.f, 0.f, 0.f, 0.f);
    if (doX) {
        *(float4*)&sm.xstep[0][bs][0] = *(const float4*)xrow;     // x[0..3]
        xnxt = *(const float4*)(xrow + 4);                        // x[4..7]
    }

    float h1o = 0.f, h2o = 0.f;     // per-lane f32 hidden (element j, batch n)
    const int TT = TSEQ + fut[0];
    float* outp = out + (size_t)(bg * NB) * (size_t)TT;
    __syncthreads();

#define STEP(IV, PAR, DOL2, DORED)                                                \
{                                                                                 \
    const int i_ = (IV);                                                          \
    if (doM) {                                                                    \
        const short8 b10 = *(const short8*)&sm.h1[PAR][n][q * 8];                 \
        const short8 b11 = *(const short8*)&sm.h1[PAR][n][32 + q * 8];            \
        if (DOL2) {                                                               \
            const short8 b20 = *(const short8*)&sm.h2[PAR][n][q * 8];             \
            const short8 b21 = *(const short8*)&sm.h2[PAR][n][32 + q * 8];        \
            const f32x4 g  = dot4(a2h, a2l, b20, b21, b2v);                       \
            const f32x4 gi = dot4(a3h, a3l, b10, b11, c2v);                       \
            const float gr = sigm(gi.x + g.x);                                    \
            const float gz = sigm(gi.y + g.y);                                    \
            const float gn = tanh_(fmaf(gr, g.z, gi.z));                          \
            const float hn = gn + gz * (h2o - gn);                                \
            h2o = hn;                                                             \
            float pout = 0.f;                                                     \
            if (jv) { sm.h2[(PAR) ^ 1][n][j] = (short)f2bf(hn); pout = wl * hn; } \
            pout += __shfl_xor(pout, 16);                                         \
            pout += __shfl_xor(pout, 32);                                         \
            if (q == 0 && n < NB) sm.part[PAR][T][n] = pout;                      \
        }                                                                         \
        {                                                                         \
            const float xv = sm.xstep[(i_ >> 2) & 1][n & 7][i_ & 3];              \
            const f32x4 a = dot4(a1h, a1l, b10, b11, b1v);                        \
            const float gr = sigm(fmaf(xv, w1r, c1r) + a.x);                      \
            const float gz = sigm(fmaf(xv, w1z, c1z) + a.y);                      \
            const float gn = tanh_(fmaf(gr, a.z, fmaf(xv, w1n, c1n)));            \
            const float hn = gn + gz * (h1o - gn);                                \
            h1o = hn;                                                             \
            if (jv) sm.h1[(PAR) ^ 1][n][j] = (short)f2bf(hn);                     \
        }                                                                         \
    } else if (w == 14) {                                                         \
        if (DORED) {                                                              \
            const float* pb = &sm.part[(PAR) ^ 1][0][0];                          \
            float v = pb[lane] + pb[64 + lane];                                   \
            v += __shfl_xor(v, 8);                                                \
            v += __shfl_xor(v, 16);                                               \
            v += __shfl_xor(v, 32);                                               \
            if (lane < 8) outp[(size_t)lane * TT + (i_ - 2)] = v + blin_r;        \
        }                                                                         \
    } else if (doX && (i_ & 3) == 3 && (i_ + 1) < TSEQ) {                         \
        *(float4*)&sm.xstep[((i_ + 1) >> 2) & 1][bs][0] = xnxt;                   \
        if (i_ + 8 < TSEQ) xnxt = *(const float4*)(xrow + i_ + 5);                \
    }                                                                             \
    __syncthreads();                                                              \
}

    // ========== MAIN LOOP: 1 barrier/step, parity-specialized unroll-2 ==========
    STEP(0, 0, false, false)
    STEP(1, 1, true,  false)
    for (int i = 2; i < TSEQ; i += 2) {
        STEP(i,     0, true, true)
        STEP(i + 1, 1, true, true)
    }

    // ========== EPILOGUE: h2(TSEQ-1), flush o(TSEQ-2) and o(TSEQ-1) ==========
    // state: h1(TSEQ-1) in h1[0], h2(TSEQ-2) in h2[0]; part[1] holds o(TSEQ-2) partials
    if (doM) {
        const short8 b10 = *(const short8*)&sm.h1[0][n][q * 8];
        const short8 b11 = *(const short8*)&sm.h1[0][n][32 + q * 8];
        const short8 b20 = *(const short8*)&sm.h2[0][n][q * 8];
        const short8 b21 = *(const short8*)&sm.h2[0][n][32 + q * 8];
        const f32x4 g  = dot4(a2h, a2l, b20, b21, b2v);
        const f32x4 gi = dot4(a3h, a3l, b10, b11, c2v);
        const float gr = sigm(gi.x + g.x);
        const float gz = sigm(gi.y + g.y);
        const float gn = tanh_(fmaf(gr, g.z, gi.z));
        const float hn = gn + gz * (h2o - gn);
        h2o = hn;
        float pout = 0.f;
        if (jv) { sm.h2[1][n][j] = (short)f2bf(hn); pout = wl * hn; }
        pout += __shfl_xor(pout, 16);
        pout += __shfl_xor(pout, 32);
        if (q == 0 && n < NB) sm.part[0][T][n] = pout;
    } else if (w == 14) {
        const float* pb = &sm.part[1][0][0];
        float v = pb[lane] + pb[64 + lane];
        v += __shfl_xor(v, 8);
        v += __shfl_xor(v, 16);
        v += __shfl_xor(v, 32);
        if (lane < 8) outp[(size_t)lane * TT + (TSEQ - 2)] = v + blin_r;
    }
    __syncthreads();
    if (w == 14) {
        const float* pb = &sm.part[0][0][0];
        float v = pb[lane] + pb[64 + lane];
        v += __shfl_xor(v, 8);
        v += __shfl_xor(v, 16);
        v += __shfl_xor(v, 32);
        if (lane < 8) {
            const float o = v + blin_r;
            sm.olds[lane] = o;
            outp[(size_t)lane * TT + (TSEQ - 1)] = o;
        }
    }
    __syncthreads();

    // ========== FUTURE LOOP: serial feedback, 3 barriers/step ==========
    int fp1 = 0, fh2 = 1;    // h1(TSEQ-1) in h1[0], h2(TSEQ-1) in h2[1]
    for (int ts = TSEQ; ts < TT; ++ts) {
        float g2r, g2z, g2n;
        if (doM) {
            const short8 b10 = *(const short8*)&sm.h1[fp1][n][q * 8];
            const short8 b11 = *(const short8*)&sm.h1[fp1][n][32 + q * 8];
            const short8 b20 = *(const short8*)&sm.h2[fh2][n][q * 8];
            const short8 b21 = *(const short8*)&sm.h2[fh2][n][32 + q * 8];
            const float  xv  = sm.olds[n & 7];
            {
                const f32x4 g = dot4(a2h, a2l, b20, b21, b2v);
                g2r = g.x; g2z = g.y; g2n = g.z;
            }
            {
                const f32x4 a = dot4(a1h, a1l, b10, b11, b1v);
                const float gr = sigm(fmaf(xv, w1r, c1r) + a.x);
                const float gz = sigm(fmaf(xv, w1z, c1z) + a.y);
                const float gn = tanh_(fmaf(gr, a.z, fmaf(xv, w1n, c1n)));
                const float hn = gn + gz * (h1o - gn);
                h1o = hn;
                if (jv) sm.h1[fp1 ^ 1][n][j] = (short)f2bf(hn);
            }
        }
        __syncthreads();
        if (doM) {
            const short8 c0 = *(const short8*)&sm.h1[fp1 ^ 1][n][q * 8];
            const short8 c1 = *(const short8*)&sm.h1[fp1 ^ 1][n][32 + q * 8];
            const f32x4 gi = dot4(a3h, a3l, c0, c1, c2v);
            const float gr = sigm(gi.x + g2r);
            const float gz = sigm(gi.y + g2z);
            const float gn = tanh_(fmaf(gr, g2n, gi.z));
            const float hn = gn + gz * (h2o - gn);
            h2o = hn;
            float pout = 0.f;
            if (jv) { sm.h2[fh2 ^ 1][n][j] = (short)f2bf(hn); pout = wl * hn; }
            pout += __shfl_xor(pout, 16);
            pout += __shfl_xor(pout, 32);
            if (q == 0 && n < NB) sm.part[0][T][n] = pout;
        }
        __syncthreads();
        if (w == 14) {
            const float* pb = &sm.part[0][0][0];
            float v = pb[lane] + pb[64 + lane];
            v += __shfl_xor(v, 8);
            v += __shfl_xor(v, 16);
            v += __shfl_xor(v, 32);
            if (lane < 8) {
                const float o = v + blin_r;
                sm.olds[lane] = o;
                outp[(size_t)lane * TT + ts] = o;
            }
        }
        __syncthreads();
        fp1 ^= 1; fh2 ^= 1;
    }
}

extern "C" void kernel_launch(void* const* d_in, const int* in_sizes, int n_in,
                              void* d_out, int out_size, void* d_ws, size_t ws_size,
                              hipStream_t stream) {
    (void)in_sizes; (void)n_in; (void)d_ws; (void)ws_size; (void)out_size;
    gru_persist<<<BB / NB, NT, 0, stream>>>(
        (const float*)d_in[0], (const int*)d_in[1],
        (const float*)d_in[2], (const float*)d_in[3], (const float*)d_in[4], (const float*)d_in[5],
        (const float*)d_in[6], (const float*)d_in[7], (const float*)d_in[8], (const float*)d_in[9],
        (const float*)d_in[10], (const float*)d_in[11],
        (float*)d_out);
}